// Round 13
// baseline (44.653 us; speedup 1.0000x reference)
//
#include <hip/hip_runtime.h>
#include <hip/hip_bf16.h>

typedef short bf16x8 __attribute__((ext_vector_type(8)));
typedef float f32x4 __attribute__((ext_vector_type(4)));
typedef unsigned int uint;

#define TOTAL (64 * 16384)
#define ITERS 2
#define RBLOCKS (TOTAL / (256 * ITERS)) // 2048
#define PBLOCKS 256                     // crit partial blocks; setup grid = 257

// d_ws layout (bytes):
//   0     : float part[256]    (crit per-block maxima)
//   2048  : float scal[8]      (wtn,win,wvn,wcn, -, pbo0, 0,0)
//   4096  : uint4 frag[13][64] (prop-MLP per-lane fragments)
#define WS_PART(ws) ((float*)(ws))
#define WS_SCAL(ws) ((float*)((char*)(ws) + 2048))
#define WS_FRAG(ws) ((uint4*)((char*)(ws) + 4096))

__device__ __forceinline__ uint bf16rne(float x) {
    uint b = __float_as_uint(x);
    return (b + 0x7fffu + ((b >> 16) & 1u)) >> 16;
}
__device__ __forceinline__ short bf16s(float x) { return (short)bf16rne(x); }
__device__ __forceinline__ uint pk2(float lo, float hi) {
    __hip_bfloat162 h2 = __float22bfloat162_rn(make_float2(lo, hi));
    uint u;
    __builtin_memcpy(&u, &h2, sizeof(u));
    return u;
}
__device__ __forceinline__ float relu_(float x) { return fmaxf(x, 0.0f); }
__device__ __forceinline__ float fast_sigmoid(float x) {
    return __builtin_amdgcn_rcpf(1.0f + __expf(-x));
}
__device__ __forceinline__ float dot4r(f32x4 v, float4 w) {
    return fmaf(relu_(v[0]), w.x, fmaf(relu_(v[1]), w.y,
           fmaf(relu_(v[2]), w.z, relu_(v[3]) * w.w)));
}
__device__ __forceinline__ bf16x8 u4bf(uint4 u) {
    bf16x8 r;
    __builtin_memcpy(&r, &u, sizeof(r));
    return r;
}
__device__ __forceinline__ uint4 bfu4(bf16x8 f) {
    uint4 u;
    __builtin_memcpy(&u, &f, sizeof(u));
    return u;
}
__device__ __forceinline__ uint4 f4u4(float4 f) {
    uint4 u;
    __builtin_memcpy(&u, &f, sizeof(u));
    return u;
}

// ---- fused setup: blocks 0..255 = crit partial max; block 256 = frag build --
__global__ __launch_bounds__(256) void setup_kernel(
        const float* __restrict__ crit,
        const float* __restrict__ pW1,  const float* __restrict__ pb1,
        const float* __restrict__ pW2,  const float* __restrict__ pb2,
        const float* __restrict__ pW3,  const float* __restrict__ pb3,
        const float* __restrict__ pWo,  const float* __restrict__ pbo,
        const float* __restrict__ w_threat, const float* __restrict__ w_impact,
        const float* __restrict__ w_vuln,   const float* __restrict__ w_ctx,
        void* __restrict__ ws, int n4) {
    if (blockIdx.x < PBLOCKS) {
        // ---------------- crit partial max ----------------
        __shared__ float smax[4];
        const int tid = threadIdx.x;
        float m = 0.0f;
        const float4* c4 = (const float4*)crit;
        for (int i = blockIdx.x * 256 + tid; i < n4; i += PBLOCKS * 256) {
            float4 v = c4[i];
            m = fmaxf(fmaxf(m, v.x), fmaxf(fmaxf(v.y, v.z), v.w));
        }
#pragma unroll
        for (int off = 32; off > 0; off >>= 1)
            m = fmaxf(m, __shfl_xor(m, off));
        if ((tid & 63) == 0) smax[tid >> 6] = m;
        __syncthreads();
        if (tid == 0)
            WS_PART(ws)[blockIdx.x] =
                fmaxf(fmaxf(smax[0], smax[1]), fmaxf(smax[2], smax[3]));
        return;
    }
    // ---------------- frag + scalar build (one wave, concurrent) -------------
    if (threadIdx.x >= 64) return;
    const int lane = threadIdx.x;
    const int g    = lane >> 4;
    const int c    = lane & 15;
    const bf16x8 z8 = {0,0,0,0,0,0,0,0};

    if (lane == 0) {
        float wt = w_threat[0], wi = w_impact[0], wv = w_vuln[0], wc = w_ctx[0];
        float inv_tw = 1.0f / (wt + wi + wv + wc);
        float* scal = WS_SCAL(ws);
        scal[0] = wt * inv_tw;
        scal[1] = wi * inv_tw;
        scal[2] = wv * inv_tw;
        scal[3] = wc * inv_tw;
        scal[4] = 0.0f;        // imul computed in risk kernel from partials
        scal[5] = pbo[0];
        scal[6] = 0.0f;
        scal[7] = 0.0f;
    }

    uint4* fr = WS_FRAG(ws);
    // 0-3: prop L1 out-tile nt (feat order [base,-,-,-,1,crit,conn,sens])
#pragma unroll
    for (int nt = 0; nt < 4; ++nt) {
        bf16x8 f = z8;
        f[0] = bf16s(pW1[nt * 16 + c]);
        f[4] = bf16s(pb1[nt * 16 + c]);
        f[5] = bf16s(pW1[64 + nt * 16 + c]);
        f[6] = bf16s(pW1[128 + nt * 16 + c]);
        f[7] = bf16s(pW1[192 + nt * 16 + c]);
        fr[nt * 64 + lane] = bfu4(f);
    }
    // 4-7: prop L2 [mt][kf]
#pragma unroll
    for (int mt = 0; mt < 2; ++mt)
#pragma unroll
        for (int kf = 0; kf < 2; ++kf) {
            bf16x8 f;
#pragma unroll
            for (int i = 0; i < 4; ++i)
                f[i] = bf16s(pW2[(kf * 32 + 4 * g + i) * 32 + mt * 16 + c]);
#pragma unroll
            for (int i = 4; i < 8; ++i)
                f[i] = bf16s(pW2[(kf * 32 + 16 + 4 * g + (i - 4)) * 32 + mt * 16 + c]);
            fr[(4 + mt * 2 + kf) * 64 + lane] = bfu4(f);
        }
    // 8: prop L3
    {
        bf16x8 f;
#pragma unroll
        for (int i = 0; i < 4; ++i) f[i] = bf16s(pW3[(4 * g + i) * 16 + c]);
#pragma unroll
        for (int i = 4; i < 8; ++i) f[i] = bf16s(pW3[(16 + 4 * g + (i - 4)) * 16 + c]);
        fr[8 * 64 + lane] = bfu4(f);
    }
    // 9-10: pb2 tiles; 11: pb3; 12: pWo
    fr[9  * 64 + lane] = f4u4(((const float4*)pb2)[g]);
    fr[10 * 64 + lane] = f4u4(((const float4*)pb2)[4 + g]);
    fr[11 * 64 + lane] = f4u4(((const float4*)pb3)[g]);
    fr[12 * 64 + lane] = f4u4(((const float4*)pWo)[g]);
}

// -------- fused risk kernel: VALU ctx-MLP + MFMA prop-MLP, ITERS=2 -----------
__global__ __launch_bounds__(256, 4) void risk_mfma_kernel(
        const float* __restrict__ tp,   const float* __restrict__ crit,
        const float* __restrict__ conn, const float* __restrict__ sens,
        const float* __restrict__ bv,   const float* __restrict__ dsv,
        const float* __restrict__ comp, const float* __restrict__ rt,
        const float* __restrict__ sev,
        const float* __restrict__ ctxW1, const float* __restrict__ ctxb1,
        const float* __restrict__ ctxW2, const float* __restrict__ ctxb2,
        const float* __restrict__ ctxW3, const float* __restrict__ ctxb3,
        const void* __restrict__ ws,
        float* __restrict__ out) {
    const int lane = threadIdx.x & 63;
    const int g    = lane >> 4;
    const f32x4 z4 = {0.f,0.f,0.f,0.f};

    const float* scal = WS_SCAL(ws);
    const float wtn = scal[0], win = scal[1], wvn = scal[2], wcn = scal[3];
    const float pbo0 = scal[5];

    // global crit max from 256 partials (per-wave, ~10 instructions, L2-hot)
    float imul;
    {
        float4 pm4 = ((const float4*)WS_PART(ws))[lane];
        float pm = fmaxf(fmaxf(pm4.x, pm4.y), fmaxf(pm4.z, pm4.w));
#pragma unroll
        for (int off = 32; off > 0; off >>= 1)
            pm = fmaxf(pm, __shfl_xor(pm, off));
        imul = (pm > 0.0f) ? __builtin_amdgcn_rcpf(fmaxf(pm, 1e-12f)) : 1.0f;
    }

    // prop frags: 13 coalesced 16B loads (loaded once, used ITERS x 4 times)
    const uint4* fr = WS_FRAG(ws);
    bf16x8 w1All[4];
#pragma unroll
    for (int nt = 0; nt < 4; ++nt) w1All[nt] = u4bf(fr[nt * 64 + lane]);
    bf16x8 w2A[2][2];
#pragma unroll
    for (int mt = 0; mt < 2; ++mt)
#pragma unroll
        for (int kf = 0; kf < 2; ++kf)
            w2A[mt][kf] = u4bf(fr[(4 + mt * 2 + kf) * 64 + lane]);
    bf16x8 w3A = u4bf(fr[8 * 64 + lane]);
    f32x4 b2i[2], b3i;
    float4 wog;
    __builtin_memcpy(&b2i[0], &fr[9  * 64 + lane], 16);
    __builtin_memcpy(&b2i[1], &fr[10 * 64 + lane], 16);
    __builtin_memcpy(&b3i,    &fr[11 * 64 + lane], 16);
    __builtin_memcpy(&wog,    &fr[12 * 64 + lane], 16);

    const int eblock = blockIdx.x * (256 * ITERS);

#pragma unroll 1
    for (int it = 0; it < ITERS; ++it) {
        const int e = eblock + it * 256 + (int)threadIdx.x;

        // ---- per-element loads ----
        float tpv = tp[e], cv = crit[e], cnv = conn[e], snv = sens[e];
        float bvv = bv[e], dvv = dsv[e], cpv = comp[e], rtv = rt[e], svv = sev[e];

        // ---- ctx MLP: per-lane f32 VALU, wave-uniform weights ----
        float invrt = __builtin_amdgcn_rcpf(rtv + 1e-6f);
        float h1[16];
#pragma unroll
        for (int j = 0; j < 16; ++j) {
            float a = ctxb1[j];
            a = fmaf(bvv,   ctxW1[j],      a);
            a = fmaf(dvv,   ctxW1[16 + j], a);
            a = fmaf(cpv,   ctxW1[32 + j], a);
            a = fmaf(invrt, ctxW1[48 + j], a);
            h1[j] = fmaxf(a, 0.0f);
        }
        float h2[8];
#pragma unroll
        for (int k = 0; k < 8; ++k) h2[k] = ctxb2[k];
#pragma unroll
        for (int j = 0; j < 16; ++j)
#pragma unroll
            for (int k = 0; k < 8; ++k)
                h2[k] = fmaf(h1[j], ctxW2[j * 8 + k], h2[k]);
        float a3 = ctxb3[0];
#pragma unroll
        for (int k = 0; k < 8; ++k)
            a3 = fmaf(fmaxf(h2[k], 0.0f), ctxW3[k], a3);
        float ctxr = fast_sigmoid(a3);

        // ---- weighted combination (per-lane) ----
        float threat = fast_sigmoid(3.0f * tpv);
        float impact = cv * imul;
        float vuln   = svv * 0.1f;
        float base   = fmaf(wcn, ctxr,
                       fmaf(wtn, threat, fmaf(win, impact, wvn * vuln)));

        // ---- prop MLP: 4 masked tile chains on MFMA ----
        uint bb  = bf16rne(base);
        uint zc  = pk2(1.0f, cv);   // k4=1.0(bias), k5=crit
        uint wc2 = pk2(cnv, snv);   // k6=conn, k7=sens
        float pv[4];
#pragma unroll
        for (int t = 0; t < 4; ++t) {
            bool sel = (g == t);
            uint4 pB;
            pB.x = sel ? bb  : 0u;
            pB.y = 0u;
            pB.z = sel ? zc  : 0u;
            pB.w = sel ? wc2 : 0u;
            bf16x8 bp = u4bf(pB);
            uint l1p[4][2];
#pragma unroll
            for (int nt = 0; nt < 4; ++nt) {
                f32x4 c1 = __builtin_amdgcn_mfma_f32_16x16x32_bf16(w1All[nt], bp, z4, 0, 0, 0);
                l1p[nt][0] = pk2(relu_(c1[0]), relu_(c1[1]));
                l1p[nt][1] = pk2(relu_(c1[2]), relu_(c1[3]));
            }
            uint4 B0 = make_uint4(l1p[0][0], l1p[0][1], l1p[1][0], l1p[1][1]);
            uint4 B1 = make_uint4(l1p[2][0], l1p[2][1], l1p[3][0], l1p[3][1]);
            bf16x8 b0 = u4bf(B0), b1 = u4bf(B1);
            uint l2p[2][2];
#pragma unroll
            for (int mt = 0; mt < 2; ++mt) {
                f32x4 acc = __builtin_amdgcn_mfma_f32_16x16x32_bf16(w2A[mt][0], b0, b2i[mt], 0, 0, 0);
                f32x4 c2  = __builtin_amdgcn_mfma_f32_16x16x32_bf16(w2A[mt][1], b1, acc, 0, 0, 0);
                l2p[mt][0] = pk2(relu_(c2[0]), relu_(c2[1]));
                l2p[mt][1] = pk2(relu_(c2[2]), relu_(c2[3]));
            }
            uint4 B3 = make_uint4(l2p[0][0], l2p[0][1], l2p[1][0], l2p[1][1]);
            f32x4 c3 = __builtin_amdgcn_mfma_f32_16x16x32_bf16(w3A, u4bf(B3), b3i, 0, 0, 0);
            pv[t] = dot4r(c3, wog);
        }
#pragma unroll
        for (int t = 0; t < 4; ++t) {
            pv[t] += __shfl_xor(pv[t], 16);
            pv[t] += __shfl_xor(pv[t], 32);
        }
        float psel = (g == 0) ? pv[0] : (g == 1) ? pv[1] : (g == 2) ? pv[2] : pv[3];
        out[e] = fast_sigmoid(psel + pbo0);
    }
}

extern "C" void kernel_launch(void* const* d_in, const int* in_sizes, int n_in,
                              void* d_out, int out_size, void* d_ws, size_t ws_size,
                              hipStream_t stream) {
    const float* tp    = (const float*)d_in[0];
    const float* crit  = (const float*)d_in[1];
    const float* conn  = (const float*)d_in[2];
    const float* sens  = (const float*)d_in[3];
    const float* bv    = (const float*)d_in[4];
    const float* dsv   = (const float*)d_in[5];
    const float* comp  = (const float*)d_in[6];
    const float* rt    = (const float*)d_in[7];
    const float* sev   = (const float*)d_in[8];
    const float* ctxW1 = (const float*)d_in[9];
    const float* ctxb1 = (const float*)d_in[10];
    const float* ctxW2 = (const float*)d_in[11];
    const float* ctxb2 = (const float*)d_in[12];
    const float* ctxW3 = (const float*)d_in[13];
    const float* ctxb3 = (const float*)d_in[14];
    const float* pW1   = (const float*)d_in[15];
    const float* pb1   = (const float*)d_in[16];
    const float* pW2   = (const float*)d_in[17];
    const float* pb2   = (const float*)d_in[18];
    const float* pW3   = (const float*)d_in[19];
    const float* pb3   = (const float*)d_in[20];
    const float* pWo   = (const float*)d_in[21];
    const float* pbo   = (const float*)d_in[22];
    const float* w_t   = (const float*)d_in[23];
    const float* w_i   = (const float*)d_in[24];
    const float* w_v   = (const float*)d_in[25];
    const float* w_c   = (const float*)d_in[26];

    float* out = (float*)d_out;

    setup_kernel<<<PBLOCKS + 1, 256, 0, stream>>>(
        crit, pW1, pb1, pW2, pb2, pW3, pb3, pWo, pbo,
        w_t, w_i, w_v, w_c, d_ws, TOTAL / 4);
    risk_mfma_kernel<<<RBLOCKS, 256, 0, stream>>>(
        tp, crit, conn, sens, bv, dsv, comp, rt, sev,
        ctxW1, ctxb1, ctxW2, ctxb2, ctxW3, ctxb3, d_ws, out);
}

// Round 14
// 37.858 us; speedup vs baseline: 1.1795x; 1.1795x over previous
//
#include <hip/hip_runtime.h>
#include <hip/hip_bf16.h>

typedef short bf16x8 __attribute__((ext_vector_type(8)));
typedef float f32x4 __attribute__((ext_vector_type(4)));
typedef float f32x16 __attribute__((ext_vector_type(16)));
typedef unsigned int uint;

#define TOTAL (64 * 16384)
#define BLOCKS (TOTAL / 256) // 4096; 4 waves/block, 64 elem/wave
#define MAXBLOCKS 256

// d_ws layout (bytes):
//   0     : float part[256]    (crit per-block maxima)
//   2048  : float scal[8]      (wtn,win,wvn,wcn, imul, pbo0, 0,0)
//   4096  : uint4 frag[16][64] (32x32-path per-lane fragments)
#define WS_PART(ws) ((float*)(ws))
#define WS_SCAL(ws) ((float*)((char*)(ws) + 2048))
#define WS_FRAG(ws) ((uint4*)((char*)(ws) + 4096))

__device__ __forceinline__ uint bf16rne(float x) {
    uint b = __float_as_uint(x);
    return (b + 0x7fffu + ((b >> 16) & 1u)) >> 16;
}
__device__ __forceinline__ short bf16s(float x) { return (short)bf16rne(x); }
__device__ __forceinline__ uint pk2(float lo, float hi) {
    __hip_bfloat162 h2 = __float22bfloat162_rn(make_float2(lo, hi));
    uint u;
    __builtin_memcpy(&u, &h2, sizeof(u));
    return u;
}
__device__ __forceinline__ float relu_(float x) { return fmaxf(x, 0.0f); }
__device__ __forceinline__ float fast_sigmoid(float x) {
    return __builtin_amdgcn_rcpf(1.0f + __expf(-x));
}
__device__ __forceinline__ bf16x8 u4bf(uint4 u) {
    bf16x8 r;
    __builtin_memcpy(&r, &u, sizeof(r));
    return r;
}
__device__ __forceinline__ uint4 bfu4(bf16x8 f) {
    uint4 u;
    __builtin_memcpy(&u, &f, sizeof(u));
    return u;
}
__device__ __forceinline__ uint4 f4u4(float4 f) {
    uint4 u;
    __builtin_memcpy(&u, &f, sizeof(u));
    return u;
}

// ------- per-block max of criticality -> part[blockIdx] ----------------------
__global__ __launch_bounds__(256) void crit_max_kernel(
        const float* __restrict__ crit, float* __restrict__ part, int n4) {
    __shared__ float smax[4];
    const int tid = threadIdx.x;
    float m = 0.0f;
    const float4* c4 = (const float4*)crit;
    for (int i = blockIdx.x * 256 + tid; i < n4; i += gridDim.x * 256) {
        float4 v = c4[i];
        m = fmaxf(fmaxf(m, v.x), fmaxf(fmaxf(v.y, v.z), v.w));
    }
#pragma unroll
    for (int off = 32; off > 0; off >>= 1)
        m = fmaxf(m, __shfl_xor(m, off));
    if ((tid & 63) == 0) smax[tid >> 6] = m;
    __syncthreads();
    if (tid == 0)
        part[blockIdx.x] = fmaxf(fmaxf(smax[0], smax[1]), fmaxf(smax[2], smax[3]));
}

// ------- one-wave prep: 32x32-path fragments + scalars -----------------------
// unit mapping used by all inter-layer chains: U = 16*kf + 4*h + (i&3) + 8*(i>>2)
__global__ __launch_bounds__(64) void prep_kernel(
        const float* __restrict__ pW1,  const float* __restrict__ pb1,
        const float* __restrict__ pW2,  const float* __restrict__ pb2,
        const float* __restrict__ pW3,  const float* __restrict__ pb3,
        const float* __restrict__ pWo,  const float* __restrict__ pbo,
        const float* __restrict__ w_threat, const float* __restrict__ w_impact,
        const float* __restrict__ w_vuln,   const float* __restrict__ w_ctx,
        void* __restrict__ ws) {
    const int lane = threadIdx.x;
    const int h    = lane >> 5;   // k-half
    const int q    = lane & 31;   // row/col
    const bf16x8 z8 = {0,0,0,0,0,0,0,0};

    {
        const float* part = WS_PART(ws);
        float4 pm4 = ((const float4*)part)[lane];
        float pm = fmaxf(fmaxf(pm4.x, pm4.y), fmaxf(pm4.z, pm4.w));
#pragma unroll
        for (int off = 32; off > 0; off >>= 1)
            pm = fmaxf(pm, __shfl_xor(pm, off));
        if (lane == 0) {
            float wt = w_threat[0], wi = w_impact[0], wv = w_vuln[0], wc = w_ctx[0];
            float inv_tw = 1.0f / (wt + wi + wv + wc);
            float* scal = WS_SCAL(ws);
            scal[0] = wt * inv_tw;
            scal[1] = wi * inv_tw;
            scal[2] = wv * inv_tw;
            scal[3] = wc * inv_tw;
            scal[4] = (pm > 0.0f) ? 1.0f / fmaxf(pm, 1e-12f) : 1.0f;
            scal[5] = pbo[0];
            scal[6] = 0.0f;
            scal[7] = 0.0f;
        }
    }

    uint4* fr = WS_FRAG(ws);
    // 0-1: L1 A, out-tile ot (rows = ot*32+q); feats at k<8 (h==0 only)
#pragma unroll
    for (int ot = 0; ot < 2; ++ot) {
        bf16x8 f = z8;
        if (h == 0) {
            f[0] = bf16s(pW1[ot * 32 + q]);          // base
            f[4] = bf16s(pb1[ot * 32 + q]);          // bias (B has 1.0 at k4)
            f[5] = bf16s(pW1[64 + ot * 32 + q]);     // crit
            f[6] = bf16s(pW1[128 + ot * 32 + q]);    // conn
            f[7] = bf16s(pW1[192 + ot * 32 + q]);    // sens
        }
        fr[ot * 64 + lane] = bfu4(f);
    }
    // 2-5: L2 A, k-frag kf: A[m=q][k=8h+i] = W2[U][q]
#pragma unroll
    for (int kf = 0; kf < 4; ++kf) {
        bf16x8 f;
#pragma unroll
        for (int i = 0; i < 8; ++i) {
            int U = 16 * kf + 4 * h + (i & 3) + 8 * (i >> 2);
            f[i] = bf16s(pW2[U * 32 + q]);
        }
        fr[(2 + kf) * 64 + lane] = bfu4(f);
    }
    // 6-7: L3 A, k-frag kf: outs in rows q<16 only
#pragma unroll
    for (int kf = 0; kf < 2; ++kf) {
        bf16x8 f = z8;
        if (q < 16) {
#pragma unroll
            for (int i = 0; i < 8; ++i) {
                int U = 16 * kf + 4 * h + (i & 3) + 8 * (i >> 2);
                f[i] = bf16s(pW3[U * 16 + q]);
            }
        }
        fr[(6 + kf) * 64 + lane] = bfu4(f);
    }
    // 8-11: b2 C-init (16 regs, row = (reg&3)+8*(reg>>2)+4h)
#pragma unroll
    for (int s = 0; s < 4; ++s) {
        float4 t;
        t.x = pb2[((4 * s + 0) & 3) + 8 * ((4 * s + 0) >> 2) + 4 * h];
        t.y = pb2[((4 * s + 1) & 3) + 8 * ((4 * s + 1) >> 2) + 4 * h];
        t.z = pb2[((4 * s + 2) & 3) + 8 * ((4 * s + 2) >> 2) + 4 * h];
        t.w = pb2[((4 * s + 3) & 3) + 8 * ((4 * s + 3) >> 2) + 4 * h];
        fr[(8 + s) * 64 + lane] = f4u4(t);
    }
    // 12-13: b3 (regs 0..7; rows all <16); 14-15: pWo (same rows)
#pragma unroll
    for (int s = 0; s < 2; ++s) {
        float4 t3, tw;
        t3.x = pb3[((4 * s + 0) & 3) + 8 * ((4 * s + 0) >> 2) + 4 * h];
        t3.y = pb3[((4 * s + 1) & 3) + 8 * ((4 * s + 1) >> 2) + 4 * h];
        t3.z = pb3[((4 * s + 2) & 3) + 8 * ((4 * s + 2) >> 2) + 4 * h];
        t3.w = pb3[((4 * s + 3) & 3) + 8 * ((4 * s + 3) >> 2) + 4 * h];
        tw.x = pWo[((4 * s + 0) & 3) + 8 * ((4 * s + 0) >> 2) + 4 * h];
        tw.y = pWo[((4 * s + 1) & 3) + 8 * ((4 * s + 1) >> 2) + 4 * h];
        tw.z = pWo[((4 * s + 2) & 3) + 8 * ((4 * s + 2) >> 2) + 4 * h];
        tw.w = pWo[((4 * s + 3) & 3) + 8 * ((4 * s + 3) >> 2) + 4 * h];
        fr[(12 + s) * 64 + lane] = f4u4(t3);
        fr[(14 + s) * 64 + lane] = f4u4(tw);
    }
}

// -------- fused risk kernel: VALU ctx-MLP + 32x32-MFMA prop-MLP --------------
__global__ __launch_bounds__(256, 3) void risk_mfma_kernel(
        const float* __restrict__ tp,   const float* __restrict__ crit,
        const float* __restrict__ conn, const float* __restrict__ sens,
        const float* __restrict__ bv,   const float* __restrict__ dsv,
        const float* __restrict__ comp, const float* __restrict__ rt,
        const float* __restrict__ sev,
        const float* __restrict__ ctxW1, const float* __restrict__ ctxb1,
        const float* __restrict__ ctxW2, const float* __restrict__ ctxb2,
        const float* __restrict__ ctxW3, const float* __restrict__ ctxb3,
        const void* __restrict__ ws,
        float* __restrict__ out) {
    const int lane = threadIdx.x & 63;
    const int h    = lane >> 5;

    const float* scal = WS_SCAL(ws);
    const float wtn = scal[0], win = scal[1], wvn = scal[2], wcn = scal[3];
    const float imul = scal[4], pbo0 = scal[5];

    // fragments: 16 coalesced 16B loads
    const uint4* fr = WS_FRAG(ws);
    bf16x8 w1A[2], w2A[4], w3A[2];
#pragma unroll
    for (int ot = 0; ot < 2; ++ot) w1A[ot] = u4bf(fr[ot * 64 + lane]);
#pragma unroll
    for (int kf = 0; kf < 4; ++kf) w2A[kf] = u4bf(fr[(2 + kf) * 64 + lane]);
#pragma unroll
    for (int kf = 0; kf < 2; ++kf) w3A[kf] = u4bf(fr[(6 + kf) * 64 + lane]);
    f32x16 b2i;
#pragma unroll
    for (int s = 0; s < 4; ++s) {
        float4 t;
        __builtin_memcpy(&t, &fr[(8 + s) * 64 + lane], 16);
        b2i[4 * s + 0] = t.x; b2i[4 * s + 1] = t.y;
        b2i[4 * s + 2] = t.z; b2i[4 * s + 3] = t.w;
    }
    f32x16 c3i;
#pragma unroll
    for (int s = 0; s < 2; ++s) {
        float4 t;
        __builtin_memcpy(&t, &fr[(12 + s) * 64 + lane], 16);
        c3i[4 * s + 0] = t.x; c3i[4 * s + 1] = t.y;
        c3i[4 * s + 2] = t.z; c3i[4 * s + 3] = t.w;
    }
#pragma unroll
    for (int r = 8; r < 16; ++r) c3i[r] = 0.0f;
    float4 wo0, wo1;
    __builtin_memcpy(&wo0, &fr[14 * 64 + lane], 16);
    __builtin_memcpy(&wo1, &fr[15 * 64 + lane], 16);

    const int e = blockIdx.x * 256 + (int)threadIdx.x;

    // ---- per-element loads ----
    float tpv = tp[e], cv = crit[e], cnv = conn[e], snv = sens[e];
    float bvv = bv[e], dvv = dsv[e], cpv = comp[e], rtv = rt[e], svv = sev[e];

    // ---- ctx MLP: per-lane f32 VALU, wave-uniform weights ----
    float invrt = __builtin_amdgcn_rcpf(rtv + 1e-6f);
    float h1[16];
#pragma unroll
    for (int j = 0; j < 16; ++j) {
        float a = ctxb1[j];
        a = fmaf(bvv,   ctxW1[j],      a);
        a = fmaf(dvv,   ctxW1[16 + j], a);
        a = fmaf(cpv,   ctxW1[32 + j], a);
        a = fmaf(invrt, ctxW1[48 + j], a);
        h1[j] = fmaxf(a, 0.0f);
    }
    float h2[8];
#pragma unroll
    for (int k = 0; k < 8; ++k) h2[k] = ctxb2[k];
#pragma unroll
    for (int j = 0; j < 16; ++j)
#pragma unroll
        for (int k = 0; k < 8; ++k)
            h2[k] = fmaf(h1[j], ctxW2[j * 8 + k], h2[k]);
    float a3 = ctxb3[0];
#pragma unroll
    for (int k = 0; k < 8; ++k)
        a3 = fmaf(fmaxf(h2[k], 0.0f), ctxW3[k], a3);
    float ctxr = fast_sigmoid(a3);

    // ---- weighted combination ----
    float threat = fast_sigmoid(3.0f * tpv);
    float impact = cv * imul;
    float vuln   = svv * 0.1f;
    float base   = fmaf(wcn, ctxr,
                   fmaf(wtn, threat, fmaf(win, impact, wvn * vuln)));

    // ---- feature words: k0=base, k4=1.0, k5=crit, k6=conn, k7=sens ----
    uint a0 = bf16rne(base);
    uint a2 = pk2(1.0f, cv);
    uint a3u = pk2(cnv, snv);
    // tile1 features: element lane^32 (h==0 lanes need upper-half elements)
    uint s0 = __shfl_xor(a0, 32);
    uint s2 = __shfl_xor(a2, 32);
    uint s3 = __shfl_xor(a3u, 32);

    const f32x16 z16 = {0.f,0.f,0.f,0.f,0.f,0.f,0.f,0.f,
                        0.f,0.f,0.f,0.f,0.f,0.f,0.f,0.f};
    float ov[2];
#pragma unroll
    for (int T = 0; T < 2; ++T) {
        uint4 pB;
        if (T == 0) {
            pB.x = (h == 0) ? a0  : 0u;
            pB.z = (h == 0) ? a2  : 0u;
            pB.w = (h == 0) ? a3u : 0u;
        } else {
            pB.x = (h == 0) ? s0  : 0u;
            pB.z = (h == 0) ? s2  : 0u;
            pB.w = (h == 0) ? s3  : 0u;
        }
        pB.y = 0u;
        bf16x8 bp = u4bf(pB);
        // L1: 64 outs via 2 out-tiles
        f32x16 d1a = __builtin_amdgcn_mfma_f32_32x32x16_bf16(w1A[0], bp, z16, 0, 0, 0);
        f32x16 d1b = __builtin_amdgcn_mfma_f32_32x32x16_bf16(w1A[1], bp, z16, 0, 0, 0);
        // pack -> L2 B-frags (C-frag IS B-frag under the unit mapping)
        uint4 B2[4];
#pragma unroll
        for (int s = 0; s < 2; ++s) {
            B2[s].x = pk2(relu_(d1a[8*s+0]), relu_(d1a[8*s+1]));
            B2[s].y = pk2(relu_(d1a[8*s+2]), relu_(d1a[8*s+3]));
            B2[s].z = pk2(relu_(d1a[8*s+4]), relu_(d1a[8*s+5]));
            B2[s].w = pk2(relu_(d1a[8*s+6]), relu_(d1a[8*s+7]));
            B2[2+s].x = pk2(relu_(d1b[8*s+0]), relu_(d1b[8*s+1]));
            B2[2+s].y = pk2(relu_(d1b[8*s+2]), relu_(d1b[8*s+3]));
            B2[2+s].z = pk2(relu_(d1b[8*s+4]), relu_(d1b[8*s+5]));
            B2[2+s].w = pk2(relu_(d1b[8*s+6]), relu_(d1b[8*s+7]));
        }
        // L2: 4 chained K-frags (full K utilization)
        f32x16 d2 = b2i;
#pragma unroll
        for (int kf = 0; kf < 4; ++kf)
            d2 = __builtin_amdgcn_mfma_f32_32x32x16_bf16(w2A[kf], u4bf(B2[kf]), d2, 0, 0, 0);
        // pack -> L3 B-frags
        uint4 B3[2];
#pragma unroll
        for (int s = 0; s < 2; ++s) {
            B3[s].x = pk2(relu_(d2[8*s+0]), relu_(d2[8*s+1]));
            B3[s].y = pk2(relu_(d2[8*s+2]), relu_(d2[8*s+3]));
            B3[s].z = pk2(relu_(d2[8*s+4]), relu_(d2[8*s+5]));
            B3[s].w = pk2(relu_(d2[8*s+6]), relu_(d2[8*s+7]));
        }
        // L3: 2 chained K-frags (outs in rows 0..15)
        f32x16 d3 = c3i;
        d3 = __builtin_amdgcn_mfma_f32_32x32x16_bf16(w3A[0], u4bf(B3[0]), d3, 0, 0, 0);
        d3 = __builtin_amdgcn_mfma_f32_32x32x16_bf16(w3A[1], u4bf(B3[1]), d3, 0, 0, 0);
        // Lo: regs 0..7 hold the lane's 8 valid L3 rows
        float p = 0.0f;
        p = fmaf(relu_(d3[0]), wo0.x, p);
        p = fmaf(relu_(d3[1]), wo0.y, p);
        p = fmaf(relu_(d3[2]), wo0.z, p);
        p = fmaf(relu_(d3[3]), wo0.w, p);
        p = fmaf(relu_(d3[4]), wo1.x, p);
        p = fmaf(relu_(d3[5]), wo1.y, p);
        p = fmaf(relu_(d3[6]), wo1.z, p);
        p = fmaf(relu_(d3[7]), wo1.w, p);
        p += __shfl_xor(p, 32);   // combine the two k-half partial sums
        ov[T] = fast_sigmoid(p + pbo0);
    }
    // lane l stores element l: lower half from tile0, upper half from tile1
    out[e] = (h == 0) ? ov[0] : ov[1];
}

extern "C" void kernel_launch(void* const* d_in, const int* in_sizes, int n_in,
                              void* d_out, int out_size, void* d_ws, size_t ws_size,
                              hipStream_t stream) {
    const float* tp    = (const float*)d_in[0];
    const float* crit  = (const float*)d_in[1];
    const float* conn  = (const float*)d_in[2];
    const float* sens  = (const float*)d_in[3];
    const float* bv    = (const float*)d_in[4];
    const float* dsv   = (const float*)d_in[5];
    const float* comp  = (const float*)d_in[6];
    const float* rt    = (const float*)d_in[7];
    const float* sev   = (const float*)d_in[8];
    const float* ctxW1 = (const float*)d_in[9];
    const float* ctxb1 = (const float*)d_in[10];
    const float* ctxW2 = (const float*)d_in[11];
    const float* ctxb2 = (const float*)d_in[12];
    const float* ctxW3 = (const float*)d_in[13];
    const float* ctxb3 = (const float*)d_in[14];
    const float* pW1   = (const float*)d_in[15];
    const float* pb1   = (const float*)d_in[16];
    const float* pW2   = (const float*)d_in[17];
    const float* pb2   = (const float*)d_in[18];
    const float* pW3   = (const float*)d_in[19];
    const float* pb3   = (const float*)d_in[20];
    const float* pWo   = (const float*)d_in[21];
    const float* pbo   = (const float*)d_in[22];
    const float* w_t   = (const float*)d_in[23];
    const float* w_i   = (const float*)d_in[24];
    const float* w_v   = (const float*)d_in[25];
    const float* w_c   = (const float*)d_in[26];

    float* out = (float*)d_out;

    crit_max_kernel<<<MAXBLOCKS, 256, 0, stream>>>(crit, WS_PART(d_ws), TOTAL / 4);
    prep_kernel<<<1, 64, 0, stream>>>(
        pW1, pb1, pW2, pb2, pW3, pb3, pWo, pbo,
        w_t, w_i, w_v, w_c, d_ws);
    risk_mfma_kernel<<<BLOCKS, 256, 0, stream>>>(
        tp, crit, conn, sens, bv, dsv, comp, rt, sev,
        ctxW1, ctxb1, ctxW2, ctxb2, ctxW3, ctxb3, d_ws, out);
}

// Round 15
// 32.918 us; speedup vs baseline: 1.3565x; 1.1501x over previous
//
#include <hip/hip_runtime.h>
#include <hip/hip_bf16.h>

typedef short bf16x8 __attribute__((ext_vector_type(8)));
typedef float f32x4 __attribute__((ext_vector_type(4)));
typedef float f32x16 __attribute__((ext_vector_type(16)));
typedef unsigned int uint;

#define TOTAL (64 * 16384)
#define BLOCKS (TOTAL / 256) // 4096; 4 waves/block, 64 elem/wave
#define PBLOCKS 256          // crit partial blocks; setup grid = 257

// d_ws layout (bytes):
//   0     : float part[256]    (crit per-block maxima)
//   2048  : float scal[8]      (wtn,win,wvn,wcn, -, pbo0, 0,0)
//   4096  : uint4 frag[16][64] (32x32-path per-lane fragments)
#define WS_PART(ws) ((float*)(ws))
#define WS_SCAL(ws) ((float*)((char*)(ws) + 2048))
#define WS_FRAG(ws) ((uint4*)((char*)(ws) + 4096))

__device__ __forceinline__ uint bf16rne(float x) {
    uint b = __float_as_uint(x);
    return (b + 0x7fffu + ((b >> 16) & 1u)) >> 16;
}
__device__ __forceinline__ short bf16s(float x) { return (short)bf16rne(x); }
__device__ __forceinline__ uint pk2(float lo, float hi) {
    __hip_bfloat162 h2 = __float22bfloat162_rn(make_float2(lo, hi));
    uint u;
    __builtin_memcpy(&u, &h2, sizeof(u));
    return u;
}
__device__ __forceinline__ float relu_(float x) { return fmaxf(x, 0.0f); }
__device__ __forceinline__ float fast_sigmoid(float x) {
    return __builtin_amdgcn_rcpf(1.0f + __expf(-x));
}
__device__ __forceinline__ bf16x8 u4bf(uint4 u) {
    bf16x8 r;
    __builtin_memcpy(&r, &u, sizeof(r));
    return r;
}
__device__ __forceinline__ uint4 bfu4(bf16x8 f) {
    uint4 u;
    __builtin_memcpy(&u, &f, sizeof(u));
    return u;
}
__device__ __forceinline__ uint4 f4u4(float4 f) {
    uint4 u;
    __builtin_memcpy(&u, &f, sizeof(u));
    return u;
}

// ---- fused setup: blocks 0..255 = crit partial max; block 256 = frag build --
// unit mapping for all inter-layer chains: U = 16*kf + 4*h + (i&3) + 8*(i>>2)
__global__ __launch_bounds__(256) void setup_kernel(
        const float* __restrict__ crit,
        const float* __restrict__ pW1,  const float* __restrict__ pb1,
        const float* __restrict__ pW2,  const float* __restrict__ pb2,
        const float* __restrict__ pW3,  const float* __restrict__ pb3,
        const float* __restrict__ pWo,  const float* __restrict__ pbo,
        const float* __restrict__ w_threat, const float* __restrict__ w_impact,
        const float* __restrict__ w_vuln,   const float* __restrict__ w_ctx,
        void* __restrict__ ws, int n4) {
    if (blockIdx.x < PBLOCKS) {
        __shared__ float smax[4];
        const int tid = threadIdx.x;
        float m = 0.0f;
        const float4* c4 = (const float4*)crit;
        for (int i = blockIdx.x * 256 + tid; i < n4; i += PBLOCKS * 256) {
            float4 v = c4[i];
            m = fmaxf(fmaxf(m, v.x), fmaxf(fmaxf(v.y, v.z), v.w));
        }
#pragma unroll
        for (int off = 32; off > 0; off >>= 1)
            m = fmaxf(m, __shfl_xor(m, off));
        if ((tid & 63) == 0) smax[tid >> 6] = m;
        __syncthreads();
        if (tid == 0)
            WS_PART(ws)[blockIdx.x] =
                fmaxf(fmaxf(smax[0], smax[1]), fmaxf(smax[2], smax[3]));
        return;
    }
    // ----- frag + scalar build (one wave, concurrent with the scan) -----
    if (threadIdx.x >= 64) return;
    const int lane = threadIdx.x;
    const int h    = lane >> 5;   // k-half
    const int q    = lane & 31;   // row/col
    const bf16x8 z8 = {0,0,0,0,0,0,0,0};

    if (lane == 0) {
        float wt = w_threat[0], wi = w_impact[0], wv = w_vuln[0], wc = w_ctx[0];
        float inv_tw = 1.0f / (wt + wi + wv + wc);
        float* scal = WS_SCAL(ws);
        scal[0] = wt * inv_tw;
        scal[1] = wi * inv_tw;
        scal[2] = wv * inv_tw;
        scal[3] = wc * inv_tw;
        scal[4] = 0.0f;        // imul computed in risk kernel from partials
        scal[5] = pbo[0];
        scal[6] = 0.0f;
        scal[7] = 0.0f;
    }

    uint4* fr = WS_FRAG(ws);
    // 0-1: L1 A, out-tile ot (rows = ot*32+q); feats at k<8 (h==0 only)
#pragma unroll
    for (int ot = 0; ot < 2; ++ot) {
        bf16x8 f = z8;
        if (h == 0) {
            f[0] = bf16s(pW1[ot * 32 + q]);          // base
            f[4] = bf16s(pb1[ot * 32 + q]);          // bias (B has 1.0 at k4)
            f[5] = bf16s(pW1[64 + ot * 32 + q]);     // crit
            f[6] = bf16s(pW1[128 + ot * 32 + q]);    // conn
            f[7] = bf16s(pW1[192 + ot * 32 + q]);    // sens
        }
        fr[ot * 64 + lane] = bfu4(f);
    }
    // 2-5: L2 A, k-frag kf: A[m=q][k=8h+i] = W2[U][q]
#pragma unroll
    for (int kf = 0; kf < 4; ++kf) {
        bf16x8 f;
#pragma unroll
        for (int i = 0; i < 8; ++i) {
            int U = 16 * kf + 4 * h + (i & 3) + 8 * (i >> 2);
            f[i] = bf16s(pW2[U * 32 + q]);
        }
        fr[(2 + kf) * 64 + lane] = bfu4(f);
    }
    // 6-7: L3 A, k-frag kf: outs in rows q<16 only
#pragma unroll
    for (int kf = 0; kf < 2; ++kf) {
        bf16x8 f = z8;
        if (q < 16) {
#pragma unroll
            for (int i = 0; i < 8; ++i) {
                int U = 16 * kf + 4 * h + (i & 3) + 8 * (i >> 2);
                f[i] = bf16s(pW3[U * 16 + q]);
            }
        }
        fr[(6 + kf) * 64 + lane] = bfu4(f);
    }
    // 8-11: b2 C-init (16 regs, row = (reg&3)+8*(reg>>2)+4h)
#pragma unroll
    for (int s = 0; s < 4; ++s) {
        float4 t;
        t.x = pb2[((4 * s + 0) & 3) + 8 * ((4 * s + 0) >> 2) + 4 * h];
        t.y = pb2[((4 * s + 1) & 3) + 8 * ((4 * s + 1) >> 2) + 4 * h];
        t.z = pb2[((4 * s + 2) & 3) + 8 * ((4 * s + 2) >> 2) + 4 * h];
        t.w = pb2[((4 * s + 3) & 3) + 8 * ((4 * s + 3) >> 2) + 4 * h];
        fr[(8 + s) * 64 + lane] = f4u4(t);
    }
    // 12-13: b3 (regs 0..7); 14-15: pWo (same rows)
#pragma unroll
    for (int s = 0; s < 2; ++s) {
        float4 t3, tw;
        t3.x = pb3[((4 * s + 0) & 3) + 8 * ((4 * s + 0) >> 2) + 4 * h];
        t3.y = pb3[((4 * s + 1) & 3) + 8 * ((4 * s + 1) >> 2) + 4 * h];
        t3.z = pb3[((4 * s + 2) & 3) + 8 * ((4 * s + 2) >> 2) + 4 * h];
        t3.w = pb3[((4 * s + 3) & 3) + 8 * ((4 * s + 3) >> 2) + 4 * h];
        tw.x = pWo[((4 * s + 0) & 3) + 8 * ((4 * s + 0) >> 2) + 4 * h];
        tw.y = pWo[((4 * s + 1) & 3) + 8 * ((4 * s + 1) >> 2) + 4 * h];
        tw.z = pWo[((4 * s + 2) & 3) + 8 * ((4 * s + 2) >> 2) + 4 * h];
        tw.w = pWo[((4 * s + 3) & 3) + 8 * ((4 * s + 3) >> 2) + 4 * h];
        fr[(12 + s) * 64 + lane] = f4u4(t3);
        fr[(14 + s) * 64 + lane] = f4u4(tw);
    }
}

// -------- fused risk kernel: VALU ctx-MLP + 32x32-MFMA prop-MLP --------------
__global__ __launch_bounds__(256, 3) void risk_mfma_kernel(
        const float* __restrict__ tp,   const float* __restrict__ crit,
        const float* __restrict__ conn, const float* __restrict__ sens,
        const float* __restrict__ bv,   const float* __restrict__ dsv,
        const float* __restrict__ comp, const float* __restrict__ rt,
        const float* __restrict__ sev,
        const float* __restrict__ ctxW1, const float* __restrict__ ctxb1,
        const float* __restrict__ ctxW2, const float* __restrict__ ctxb2,
        const float* __restrict__ ctxW3, const float* __restrict__ ctxb3,
        const void* __restrict__ ws,
        float* __restrict__ out) {
    const int lane = threadIdx.x & 63;
    const int h    = lane >> 5;

    const float* scal = WS_SCAL(ws);
    const float wtn = scal[0], win = scal[1], wvn = scal[2], wcn = scal[3];
    const float pbo0 = scal[5];

    // global crit max from 256 partials (per-wave, ~10 instructions, L2-hot)
    float imul;
    {
        float4 pm4 = ((const float4*)WS_PART(ws))[lane];
        float pm = fmaxf(fmaxf(pm4.x, pm4.y), fmaxf(pm4.z, pm4.w));
#pragma unroll
        for (int off = 32; off > 0; off >>= 1)
            pm = fmaxf(pm, __shfl_xor(pm, off));
        imul = (pm > 0.0f) ? __builtin_amdgcn_rcpf(fmaxf(pm, 1e-12f)) : 1.0f;
    }

    // fragments: 16 coalesced 16B loads
    const uint4* fr = WS_FRAG(ws);
    bf16x8 w1A[2], w2A[4], w3A[2];
#pragma unroll
    for (int ot = 0; ot < 2; ++ot) w1A[ot] = u4bf(fr[ot * 64 + lane]);
#pragma unroll
    for (int kf = 0; kf < 4; ++kf) w2A[kf] = u4bf(fr[(2 + kf) * 64 + lane]);
#pragma unroll
    for (int kf = 0; kf < 2; ++kf) w3A[kf] = u4bf(fr[(6 + kf) * 64 + lane]);
    f32x16 b2i;
#pragma unroll
    for (int s = 0; s < 4; ++s) {
        float4 t;
        __builtin_memcpy(&t, &fr[(8 + s) * 64 + lane], 16);
        b2i[4 * s + 0] = t.x; b2i[4 * s + 1] = t.y;
        b2i[4 * s + 2] = t.z; b2i[4 * s + 3] = t.w;
    }
    f32x16 c3i;
#pragma unroll
    for (int s = 0; s < 2; ++s) {
        float4 t;
        __builtin_memcpy(&t, &fr[(12 + s) * 64 + lane], 16);
        c3i[4 * s + 0] = t.x; c3i[4 * s + 1] = t.y;
        c3i[4 * s + 2] = t.z; c3i[4 * s + 3] = t.w;
    }
#pragma unroll
    for (int r = 8; r < 16; ++r) c3i[r] = 0.0f;
    float4 wo0, wo1;
    __builtin_memcpy(&wo0, &fr[14 * 64 + lane], 16);
    __builtin_memcpy(&wo1, &fr[15 * 64 + lane], 16);

    const int e = blockIdx.x * 256 + (int)threadIdx.x;

    // ---- per-element loads ----
    float tpv = tp[e], cv = crit[e], cnv = conn[e], snv = sens[e];
    float bvv = bv[e], dvv = dsv[e], cpv = comp[e], rtv = rt[e], svv = sev[e];

    // ---- ctx MLP: per-lane f32 VALU, wave-uniform weights ----
    float invrt = __builtin_amdgcn_rcpf(rtv + 1e-6f);
    float h1[16];
#pragma unroll
    for (int j = 0; j < 16; ++j) {
        float a = ctxb1[j];
        a = fmaf(bvv,   ctxW1[j],      a);
        a = fmaf(dvv,   ctxW1[16 + j], a);
        a = fmaf(cpv,   ctxW1[32 + j], a);
        a = fmaf(invrt, ctxW1[48 + j], a);
        h1[j] = fmaxf(a, 0.0f);
    }
    float h2[8];
#pragma unroll
    for (int k = 0; k < 8; ++k) h2[k] = ctxb2[k];
#pragma unroll
    for (int j = 0; j < 16; ++j)
#pragma unroll
        for (int k = 0; k < 8; ++k)
            h2[k] = fmaf(h1[j], ctxW2[j * 8 + k], h2[k]);
    float a3 = ctxb3[0];
#pragma unroll
    for (int k = 0; k < 8; ++k)
        a3 = fmaf(fmaxf(h2[k], 0.0f), ctxW3[k], a3);
    float ctxr = fast_sigmoid(a3);

    // ---- weighted combination ----
    float threat = fast_sigmoid(3.0f * tpv);
    float impact = cv * imul;
    float vuln   = svv * 0.1f;
    float base   = fmaf(wcn, ctxr,
                   fmaf(wtn, threat, fmaf(win, impact, wvn * vuln)));

    // ---- feature words: k0=base, k4=1.0, k5=crit, k6=conn, k7=sens ----
    uint a0 = bf16rne(base);
    uint a2 = pk2(1.0f, cv);
    uint a3u = pk2(cnv, snv);
    uint s0 = __shfl_xor(a0, 32);
    uint s2 = __shfl_xor(a2, 32);
    uint s3 = __shfl_xor(a3u, 32);

    const f32x16 z16 = {0.f,0.f,0.f,0.f,0.f,0.f,0.f,0.f,
                        0.f,0.f,0.f,0.f,0.f,0.f,0.f,0.f};
    float ov[2];
#pragma unroll
    for (int T = 0; T < 2; ++T) {
        uint4 pB;
        if (T == 0) {
            pB.x = (h == 0) ? a0  : 0u;
            pB.z = (h == 0) ? a2  : 0u;
            pB.w = (h == 0) ? a3u : 0u;
        } else {
            pB.x = (h == 0) ? s0  : 0u;
            pB.z = (h == 0) ? s2  : 0u;
            pB.w = (h == 0) ? s3  : 0u;
        }
        pB.y = 0u;
        bf16x8 bp = u4bf(pB);
        // L1: 64 outs via 2 out-tiles
        f32x16 d1a = __builtin_amdgcn_mfma_f32_32x32x16_bf16(w1A[0], bp, z16, 0, 0, 0);
        f32x16 d1b = __builtin_amdgcn_mfma_f32_32x32x16_bf16(w1A[1], bp, z16, 0, 0, 0);
        // pack -> L2 B-frags (C-frag IS B-frag under the unit mapping)
        uint4 B2[4];
#pragma unroll
        for (int s = 0; s < 2; ++s) {
            B2[s].x = pk2(relu_(d1a[8*s+0]), relu_(d1a[8*s+1]));
            B2[s].y = pk2(relu_(d1a[8*s+2]), relu_(d1a[8*s+3]));
            B2[s].z = pk2(relu_(d1a[8*s+4]), relu_(d1a[8*s+5]));
            B2[s].w = pk2(relu_(d1a[8*s+6]), relu_(d1a[8*s+7]));
            B2[2+s].x = pk2(relu_(d1b[8*s+0]), relu_(d1b[8*s+1]));
            B2[2+s].y = pk2(relu_(d1b[8*s+2]), relu_(d1b[8*s+3]));
            B2[2+s].z = pk2(relu_(d1b[8*s+4]), relu_(d1b[8*s+5]));
            B2[2+s].w = pk2(relu_(d1b[8*s+6]), relu_(d1b[8*s+7]));
        }
        // L2: 4 chained K-frags (full K utilization)
        f32x16 d2 = b2i;
#pragma unroll
        for (int kf = 0; kf < 4; ++kf)
            d2 = __builtin_amdgcn_mfma_f32_32x32x16_bf16(w2A[kf], u4bf(B2[kf]), d2, 0, 0, 0);
        // pack -> L3 B-frags
        uint4 B3[2];
#pragma unroll
        for (int s = 0; s < 2; ++s) {
            B3[s].x = pk2(relu_(d2[8*s+0]), relu_(d2[8*s+1]));
            B3[s].y = pk2(relu_(d2[8*s+2]), relu_(d2[8*s+3]));
            B3[s].z = pk2(relu_(d2[8*s+4]), relu_(d2[8*s+5]));
            B3[s].w = pk2(relu_(d2[8*s+6]), relu_(d2[8*s+7]));
        }
        // L3: 2 chained K-frags (outs in rows 0..15)
        f32x16 d3 = c3i;
        d3 = __builtin_amdgcn_mfma_f32_32x32x16_bf16(w3A[0], u4bf(B3[0]), d3, 0, 0, 0);
        d3 = __builtin_amdgcn_mfma_f32_32x32x16_bf16(w3A[1], u4bf(B3[1]), d3, 0, 0, 0);
        // Lo: regs 0..7 hold the lane's 8 valid L3 rows
        float p = 0.0f;
        p = fmaf(relu_(d3[0]), wo0.x, p);
        p = fmaf(relu_(d3[1]), wo0.y, p);
        p = fmaf(relu_(d3[2]), wo0.z, p);
        p = fmaf(relu_(d3[3]), wo0.w, p);
        p = fmaf(relu_(d3[4]), wo1.x, p);
        p = fmaf(relu_(d3[5]), wo1.y, p);
        p = fmaf(relu_(d3[6]), wo1.z, p);
        p = fmaf(relu_(d3[7]), wo1.w, p);
        p += __shfl_xor(p, 32);   // combine the two k-half partial sums
        ov[T] = fast_sigmoid(p + pbo0);
    }
    out[e] = (h == 0) ? ov[0] : ov[1];
}

extern "C" void kernel_launch(void* const* d_in, const int* in_sizes, int n_in,
                              void* d_out, int out_size, void* d_ws, size_t ws_size,
                              hipStream_t stream) {
    const float* tp    = (const float*)d_in[0];
    const float* crit  = (const float*)d_in[1];
    const float* conn  = (const float*)d_in[2];
    const float* sens  = (const float*)d_in[3];
    const float* bv    = (const float*)d_in[4];
    const float* dsv   = (const float*)d_in[5];
    const float* comp  = (const float*)d_in[6];
    const float* rt    = (const float*)d_in[7];
    const float* sev   = (const float*)d_in[8];
    const float* ctxW1 = (const float*)d_in[9];
    const float* ctxb1 = (const float*)d_in[10];
    const float* ctxW2 = (const float*)d_in[11];
    const float* ctxb2 = (const float*)d_in[12];
    const float* ctxW3 = (const float*)d_in[13];
    const float* ctxb3 = (const float*)d_in[14];
    const float* pW1   = (const float*)d_in[15];
    const float* pb1   = (const float*)d_in[16];
    const float* pW2   = (const float*)d_in[17];
    const float* pb2   = (const float*)d_in[18];
    const float* pW3   = (const float*)d_in[19];
    const float* pb3   = (const float*)d_in[20];
    const float* pWo   = (const float*)d_in[21];
    const float* pbo   = (const float*)d_in[22];
    const float* w_t   = (const float*)d_in[23];
    const float* w_i   = (const float*)d_in[24];
    const float* w_v   = (const float*)d_in[25];
    const float* w_c   = (const float*)d_in[26];

    float* out = (float*)d_out;

    setup_kernel<<<PBLOCKS + 1, 256, 0, stream>>>(
        crit, pW1, pb1, pW2, pb2, pW3, pb3, pWo, pbo,
        w_t, w_i, w_v, w_c, d_ws, TOTAL / 4);
    risk_mfma_kernel<<<BLOCKS, 256, 0, stream>>>(
        tp, crit, conn, sens, bv, dsv, comp, rt, sev,
        ctxW1, ctxb1, ctxW2, ctxb2, ctxW3, ctxb3, d_ws, out);
}